// Round 11
// baseline (265.514 us; speedup 1.0000x reference)
//
#include <hip/hip_runtime.h>
#include <math.h>

#define T 2048
#define HIDDEN 2048
#define NH 16
#define NKV 4
#define HD 128
#define QKV_N 3072   // (16 + 2*4) * 128
#define Q_SIZE 2048  // 16*128
#define KV_SIZE 512  // 4*128

typedef __attribute__((ext_vector_type(8))) short short8;
typedef __attribute__((ext_vector_type(4))) short short4v;
typedef __attribute__((ext_vector_type(4))) float floatx4;

__device__ __forceinline__ unsigned short f2bf(float f) {
    union { float f; unsigned int u; } v; v.f = f;
    unsigned int u = v.u;
    u += 0x7fffu + ((u >> 16) & 1u);   // round-to-nearest-even
    return (unsigned short)(u >> 16);
}

// async global->LDS, 16B per lane; LDS dest = wave-uniform base + lane*16 (HW adds it)
__device__ __forceinline__ void gload_lds16(const unsigned short* g, unsigned short* l) {
    __builtin_amdgcn_global_load_lds((const __attribute__((address_space(1))) unsigned int*)g,
                                     (__attribute__((address_space(3))) unsigned int*)l, 16, 0, 0);
}

// ---------------- fused prep: convert hb + transpose wqt + transpose wot + cos/sin ----------------
// grid ranges: [0,4096) convert, [4096,10240) wqt, [10240,14336) wot, [14336,14848) cossin
__global__ __launch_bounds__(256) void prep_misc(const float* __restrict__ hidden,
                                                 const float* __restrict__ w_qkv,
                                                 const float* __restrict__ w_o,
                                                 const int* __restrict__ positions,
                                                 unsigned short* __restrict__ hb,
                                                 unsigned short* __restrict__ wqt,
                                                 unsigned short* __restrict__ wot,
                                                 float* __restrict__ cosT,
                                                 float* __restrict__ sinT) {
    __shared__ float tile[32][33];
    const int b = blockIdx.x;
    const int tid = threadIdx.x;
    const int tx = tid & 31, ty = tid >> 5;

    if (b < 4096) {
        int i = (b * 256 + tid) * 4;
        float4 v = *(const float4*)(hidden + i);
        hb[i]     = f2bf(v.x);
        hb[i + 1] = f2bf(v.y);
        hb[i + 2] = f2bf(v.z);
        hb[i + 3] = f2bf(v.w);
    } else if (b < 10240) {
        int idx = b - 4096;
        int c0 = (idx % 96) * 32, r0 = (idx / 96) * 32;
#pragma unroll
        for (int i = 0; i < 4; ++i)
            tile[ty + i * 8][tx] = w_qkv[(long)(r0 + ty + i * 8) * QKV_N + c0 + tx];
        __syncthreads();
#pragma unroll
        for (int i = 0; i < 4; ++i)
            wqt[(long)(c0 + ty + i * 8) * HIDDEN + r0 + tx] = f2bf(tile[tx][ty + i * 8]);
    } else if (b < 14336) {
        int idx = b - 10240;
        int c0 = (idx % 64) * 32, r0 = (idx / 64) * 32;
#pragma unroll
        for (int i = 0; i < 4; ++i)
            tile[ty + i * 8][tx] = w_o[(long)(r0 + ty + i * 8) * HIDDEN + c0 + tx];
        __syncthreads();
#pragma unroll
        for (int i = 0; i < 4; ++i)
            wot[(long)(c0 + ty + i * 8) * HIDDEN + r0 + tx] = f2bf(tile[tx][ty + i * 8]);
    } else {
        int idx = b - 14336;
        int t = idx * 4 + (tid >> 6);
        int j = tid & 63;
        int row = (j >= 44) ? 0 : ((j & 1) ? 2 : 1);
        int pos = positions[row * T + t];
        float invf = exp2f((float)j * -0.29580571f);   // log2(500000)/64
        float ang = (float)pos * invf;
        cosT[t * 64 + j] = cosf(ang);
        sinT[t * 64 + j] = sinf(ang);
    }
}

// ---------------- qkv GEMM: 64x128 tile (3 blocks/CU), dbuf async, rope fused ----------------
__global__ __launch_bounds__(256) void gemm_qkv(const unsigned short* __restrict__ A,
                                                const unsigned short* __restrict__ B,
                                                const float* __restrict__ cosT,
                                                const float* __restrict__ sinT,
                                                unsigned short* __restrict__ qb,
                                                unsigned short* __restrict__ kb,
                                                unsigned short* __restrict__ vt) {
    __shared__ __align__(16) unsigned short As[2][64 * 32];    // 2 x 4 KB
    __shared__ __align__(16) unsigned short Bs[2][128 * 32];   // 2 x 8 KB
    const int K = HIDDEN;
    const int tid = threadIdx.x;
    const int wv = tid >> 6;
    const int lane = tid & 63;
    const int m = lane & 15, qd = lane >> 4;
    const unsigned short* Ab = A + (long)(blockIdx.x * 64) * K;
    const unsigned short* Bb = B + (long)(blockIdx.y * 128) * K;
    const int srow = tid >> 2;          // 0..63
    const int scol = (tid & 3) * 8;

    floatx4 acc[4][2];
#pragma unroll
    for (int i = 0; i < 4; ++i)
#pragma unroll
        for (int j = 0; j < 2; ++j) acc[i][j] = (floatx4){0.f, 0.f, 0.f, 0.f};

#define QKV_STAGE(buf, k0)                                                                \
    do {                                                                                  \
        gload_lds16(Ab + (long)srow * K + (k0) + scol,        &As[buf][wv * 512]);        \
        gload_lds16(Bb + (long)srow * K + (k0) + scol,        &Bs[buf][wv * 512]);        \
        gload_lds16(Bb + (long)(64 + srow) * K + (k0) + scol, &Bs[buf][2048 + wv * 512]); \
    } while (0)

    QKV_STAGE(0, 0);
    int cur = 0;
    for (int k0 = 0; k0 < K; k0 += 32) {
        __syncthreads();                       // buf[cur] landed; prev readers of buf[cur^1] done
        if (k0 + 32 < K) QKV_STAGE(cur ^ 1, k0 + 32);
        short8 a[4], b[2];
#pragma unroll
        for (int i = 0; i < 4; ++i) a[i] = *(const short8*)&As[cur][(i * 16 + m) * 32 + qd * 8];
#pragma unroll
        for (int j = 0; j < 2; ++j) b[j] = *(const short8*)&Bs[cur][(wv * 32 + j * 16 + m) * 32 + qd * 8];
#pragma unroll
        for (int i = 0; i < 4; ++i)
#pragma unroll
            for (int j = 0; j < 2; ++j)
                acc[i][j] = __builtin_amdgcn_mfma_f32_16x16x32_bf16(a[i], b[j], acc[i][j], 0, 0, 0);
        cur ^= 1;
    }
#undef QKV_STAGE

    const int by = blockIdx.y;
    if (by < 20) {
        // rope path (q: by<16, k: 16..19); pairs are adjacent cols -> shfl_xor(val,1)
        const float sgn = (m & 1) ? 1.f : -1.f;
        const float qscale = 0.08838834764831845f;   // 1/sqrt(128)
#pragma unroll
        for (int i = 0; i < 4; ++i) {
#pragma unroll
            for (int r = 0; r < 4; ++r) {
                const int t = blockIdx.x * 64 + i * 16 + qd * 4 + r;
                const float* ct = cosT + t * 64;
                const float* st = sinT + t * 64;
#pragma unroll
                for (int j = 0; j < 2; ++j) {
                    const int cq = wv * 32 + j * 16 + m;
                    const int j2 = cq >> 1;
                    float val = acc[i][j][r];
                    float prt = __shfl_xor(val, 1);
                    float o = val * ct[j2] + sgn * prt * st[j2];
                    const int col = by * 128 + cq;
                    if (by < 16) qb[(long)t * Q_SIZE + col] = f2bf(o * qscale);
                    else         kb[(long)t * KV_SIZE + (col - 2048)] = f2bf(o);
                }
            }
        }
    } else {
        // v path: write V^T directly: vt[g][d][t], 4 consecutive t per acc -> short4 stores
        const int g = by - 20;
#pragma unroll
        for (int i = 0; i < 4; ++i)
#pragma unroll
            for (int j = 0; j < 2; ++j) {
                const int d = wv * 32 + j * 16 + m;
                const int t0 = blockIdx.x * 64 + i * 16 + qd * 4;
                unsigned short o4[4];
#pragma unroll
                for (int r = 0; r < 4; ++r) o4[r] = f2bf(acc[i][j][r]);
                *(short4v*)&vt[((long)g * HD + d) * T + t0] = *(short4v*)o4;
            }
    }
}

// ---------------- out GEMM: 64x128 tile (2 blocks/CU), dbuf async: C(fp32) = A * B^T ----------
__global__ __launch_bounds__(256) void gemm_out(const unsigned short* __restrict__ A,
                                                const unsigned short* __restrict__ B,
                                                float* __restrict__ C,
                                                int K, int ldc) {
    __shared__ __align__(16) unsigned short As[2][64 * 32];
    __shared__ __align__(16) unsigned short Bs[2][128 * 32];
    const int tid = threadIdx.x;
    const int wv = tid >> 6;
    const int lane = tid & 63;
    const int m = lane & 15, qd = lane >> 4;
    const unsigned short* Ab = A + (long)(blockIdx.x * 64) * K;
    const unsigned short* Bb = B + (long)(blockIdx.y * 128) * K;
    const int srow = tid >> 2;
    const int scol = (tid & 3) * 8;

    floatx4 acc[4][2];
#pragma unroll
    for (int i = 0; i < 4; ++i)
#pragma unroll
        for (int j = 0; j < 2; ++j) acc[i][j] = (floatx4){0.f, 0.f, 0.f, 0.f};

#define OUT_STAGE(buf, k0)                                                                \
    do {                                                                                  \
        gload_lds16(Ab + (long)srow * K + (k0) + scol,        &As[buf][wv * 512]);        \
        gload_lds16(Bb + (long)srow * K + (k0) + scol,        &Bs[buf][wv * 512]);        \
        gload_lds16(Bb + (long)(64 + srow) * K + (k0) + scol, &Bs[buf][2048 + wv * 512]); \
    } while (0)

    OUT_STAGE(0, 0);
    int cur = 0;
    for (int k0 = 0; k0 < K; k0 += 32) {
        __syncthreads();
        if (k0 + 32 < K) OUT_STAGE(cur ^ 1, k0 + 32);
        short8 a[4], b[2];
#pragma unroll
        for (int i = 0; i < 4; ++i) a[i] = *(const short8*)&As[cur][(i * 16 + m) * 32 + qd * 8];
#pragma unroll
        for (int j = 0; j < 2; ++j) b[j] = *(const short8*)&Bs[cur][(wv * 32 + j * 16 + m) * 32 + qd * 8];
#pragma unroll
        for (int i = 0; i < 4; ++i)
#pragma unroll
            for (int j = 0; j < 2; ++j)
                acc[i][j] = __builtin_amdgcn_mfma_f32_16x16x32_bf16(a[i], b[j], acc[i][j], 0, 0, 0);
        cur ^= 1;
    }
#undef OUT_STAGE

#pragma unroll
    for (int i = 0; i < 4; ++i)
#pragma unroll
        for (int j = 0; j < 2; ++j)
#pragma unroll
            for (int r = 0; r < 4; ++r)
                C[(long)(blockIdx.x * 64 + i * 16 + qd * 4 + r) * ldc +
                  blockIdx.y * 128 + wv * 32 + j * 16 + m] = acc[i][j][r];
}

// ---------------- flash attention v8: no K-split, direct normalized output ----------------
// grid(256): bx = h*16 + c16. Block runs full causal ranges for qt=c16 then qt=15-c16:
// (2*qt+2) + (2*(15-qt)+2) = 34 tile-iters for every block — balanced without any split.
// Epilogue divides by lrow in-register and writes bf16 ab directly (no Opart/combine).
__global__ __launch_bounds__(256, 2) void flash_attn(const unsigned short* __restrict__ qb,
                                                     const unsigned short* __restrict__ kb,
                                                     const unsigned short* __restrict__ vt,
                                                     unsigned short* __restrict__ ab) {
    __shared__ __align__(16) unsigned short Kbuf[2][64 * 128];   // 32 KB
    __shared__ __align__(16) unsigned short Vbuf[128 * 64];      // 16 KB
    __shared__ __align__(16) unsigned short Pls[4][32 * 72];     // 18.4 KB

    const int tid = threadIdx.x;
    const int wv = tid >> 6;
    const int lane = tid & 63;
    const int m = lane & 15;
    const int qd = lane >> 4;

    const int h = blockIdx.x >> 4;
    const int c16 = blockIdx.x & 15;
    const int g = h >> 2;
    unsigned short* myP = Pls[wv];

    for (int seg = 0; seg < 2; ++seg) {
        const int qt = seg ? (15 - c16) : c16;
        const int jt1 = 2 * qt + 2;          // full causal range for this 128-row Q tile
        const int q0 = qt * 128;

        short8 aq[2][4];
#pragma unroll
        for (int s = 0; s < 2; ++s)
#pragma unroll
            for (int kk = 0; kk < 4; ++kk)
                aq[s][kk] = *(const short8*)(qb + (long)(q0 + s * 64 + wv * 16 + m) * Q_SIZE +
                                             h * HD + kk * 32 + qd * 8);

        floatx4 acc_o[2][8];
#pragma unroll
        for (int s = 0; s < 2; ++s)
#pragma unroll
            for (int nb = 0; nb < 8; ++nb) acc_o[s][nb] = (floatx4){0.f, 0.f, 0.f, 0.f};
        float mrow[2] = {-1e30f, -1e30f};
        float lrow[2] = {0.f, 0.f};

        // stage first K tile (XOR chunk swizzle c^(r&15))
#pragma unroll
        for (int i = 0; i < 4; ++i) {
            int s_ = i * 256 + tid;
            int r = s_ >> 4, c = (s_ & 15) ^ (r & 15);
            gload_lds16(kb + (long)r * KV_SIZE + g * HD + c * 8,
                        &Kbuf[0][i * 2048 + wv * 512]);
        }
        int cur = 0;
        for (int jt = 0; jt < jt1; ++jt) {
            __syncthreads();   // K[cur] landed; all prior LDS readers done

            if (jt + 1 < jt1) {   // K prefetch -> other buffer (full iter to land)
#pragma unroll
                for (int i = 0; i < 4; ++i) {
                    int s_ = i * 256 + tid;
                    int r = s_ >> 4, c = (s_ & 15) ^ (r & 15);
                    gload_lds16(kb + (long)((jt + 1) * 64 + r) * KV_SIZE + g * HD + c * 8,
                                &Kbuf[cur ^ 1][i * 2048 + wv * 512]);
                }
            }
            // V for CURRENT tile (single buffer; consumed after mid barrier)
#pragma unroll
            for (int i = 0; i < 4; ++i) {
                int s_ = i * 256 + tid;
                int r = s_ >> 3, c = (s_ & 7) ^ (r & 7);
                gload_lds16(vt + ((long)g * HD + r) * T + jt * 64 + c * 8,
                            &Vbuf[i * 2048 + wv * 512]);
            }

            // S^T = K Q^T for both q-sets, sharing K fragment loads
            floatx4 acc_s[2][4];
#pragma unroll
            for (int s = 0; s < 2; ++s)
#pragma unroll
                for (int c = 0; c < 4; ++c) acc_s[s][c] = (floatx4){0.f, 0.f, 0.f, 0.f};
#pragma unroll
            for (int kk = 0; kk < 4; ++kk) {
#pragma unroll
                for (int c = 0; c < 4; ++c) {
                    short8 ak = *(const short8*)&Kbuf[cur][(c * 16 + m) * 128 +
                                                           (((4 * kk + qd) ^ m) * 8)];
                    acc_s[0][c] = __builtin_amdgcn_mfma_f32_16x16x32_bf16(ak, aq[0][kk], acc_s[0][c], 0, 0, 0);
                    acc_s[1][c] = __builtin_amdgcn_mfma_f32_16x16x32_bf16(ak, aq[1][kk], acc_s[1][c], 0, 0, 0);
                }
            }

            // per-set online softmax + P write
#pragma unroll
            for (int s = 0; s < 2; ++s) {
                const int dg = 2 * qt + s;
                if (jt >= dg) {
                    const bool full = (jt > dg);
#pragma unroll
                    for (int c = 0; c < 4; ++c)
#pragma unroll
                        for (int r = 0; r < 4; ++r)
                            if (full || (c * 16 + qd * 4 + r > wv * 16 + m)) acc_s[s][c][r] = -1e30f;
                }
                float mx = acc_s[s][0][0];
#pragma unroll
                for (int c = 0; c < 4; ++c)
#pragma unroll
                    for (int r = 0; r < 4; ++r) mx = fmaxf(mx, acc_s[s][c][r]);
                mx = fmaxf(mx, __shfl_xor(mx, 16));
                mx = fmaxf(mx, __shfl_xor(mx, 32));
                float mnew = fmaxf(mrow[s], mx);
                float alpha = __expf(mrow[s] - mnew);
                mrow[s] = mnew;

                float pv[4][4];
                float lsum = 0.f;
#pragma unroll
                for (int c = 0; c < 4; ++c)
#pragma unroll
                    for (int r = 0; r < 4; ++r) {
                        pv[c][r] = __expf(acc_s[s][c][r] - mnew);
                        lsum += pv[c][r];
                    }
                lsum += __shfl_xor(lsum, 16);
                lsum += __shfl_xor(lsum, 32);
                lrow[s] = lrow[s] * alpha + lsum;
#pragma unroll
                for (int nb = 0; nb < 8; ++nb)
#pragma unroll
                    for (int r = 0; r < 4; ++r) acc_o[s][nb][r] *= alpha;
#pragma unroll
                for (int c = 0; c < 4; ++c) {
                    short4v pk = {(short)f2bf(pv[c][0]), (short)f2bf(pv[c][1]),
                                  (short)f2bf(pv[c][2]), (short)f2bf(pv[c][3])};
                    *(short4v*)&myP[(s * 16 + m) * 72 + c * 16 + qd * 4] = pk;
                }
            }

            __syncthreads();   // V landed (and block-wide sync)

            // PV for both sets, sharing V fragment loads
#pragma unroll
            for (int kk = 0; kk < 2; ++kk) {
                short8 pa0 = *(const short8*)&myP[m * 72 + kk * 32 + qd * 8];
                short8 pa1 = *(const short8*)&myP[(16 + m) * 72 + kk * 32 + qd * 8];
#pragma unroll
                for (int nb = 0; nb < 8; ++nb) {
                    short8 av = *(const short8*)&Vbuf[(nb * 16 + m) * 64 +
                                                      (((4 * kk + qd) ^ (m & 7)) * 8)];
                    acc_o[0][nb] = __builtin_amdgcn_mfma_f32_16x16x32_bf16(av, pa0, acc_o[0][nb], 0, 0, 0);
                    acc_o[1][nb] = __builtin_amdgcn_mfma_f32_16x16x32_bf16(av, pa1, acc_o[1][nb], 0, 0, 0);
                }
            }
            cur ^= 1;
        }

        // epilogue: normalize and write bf16 directly (no partials)
#pragma unroll
        for (int s = 0; s < 2; ++s) {
            const float inv = 1.f / lrow[s];
            const long trow = q0 + s * 64 + wv * 16 + m;
#pragma unroll
            for (int nb = 0; nb < 8; ++nb) {
                unsigned short o4[4];
#pragma unroll
                for (int r = 0; r < 4; ++r) o4[r] = f2bf(acc_o[s][nb][r] * inv);
                *(short4v*)&ab[trow * Q_SIZE + h * HD + nb * 16 + qd * 4] = *(short4v*)o4;
            }
        }
    }
}

extern "C" void kernel_launch(void* const* d_in, const int* in_sizes, int n_in,
                              void* d_out, int out_size, void* d_ws, size_t ws_size,
                              hipStream_t stream) {
    const int* positions = (const int*)d_in[0];
    const float* hidden  = (const float*)d_in[1];
    const float* w_qkv   = (const float*)d_in[2];
    const float* w_o     = (const float*)d_in[3];
    float* out = (float*)d_out;

    char* p = (char*)d_ws;
    auto alloc = [&](size_t bytes) { char* r = p; p += (bytes + 255) & ~(size_t)255; return r; };
    float* cosT = (float*)alloc((size_t)T * 64 * 4);
    float* sinT = (float*)alloc((size_t)T * 64 * 4);
    unsigned short* hb  = (unsigned short*)alloc((size_t)T * HIDDEN * 2);
    unsigned short* wqt = (unsigned short*)alloc((size_t)QKV_N * HIDDEN * 2);
    unsigned short* wot = (unsigned short*)alloc((size_t)HIDDEN * HIDDEN * 2);
    unsigned short* qb  = (unsigned short*)alloc((size_t)T * Q_SIZE * 2);
    unsigned short* kb  = (unsigned short*)alloc((size_t)T * KV_SIZE * 2);
    unsigned short* vt  = (unsigned short*)alloc((size_t)T * KV_SIZE * 2);
    unsigned short* ab  = (unsigned short*)alloc((size_t)T * Q_SIZE * 2);

    // 1) fused prep (convert + 2 transposes + cos/sin tables)
    prep_misc<<<dim3(14848), 256, 0, stream>>>(hidden, w_qkv, w_o, positions,
                                               hb, wqt, wot, cosT, sinT);
    // 2) fused qkv projection + rope -> qb (scaled), kb, vt (64x128 tiles, 768 blocks)
    gemm_qkv<<<dim3(T / 64, QKV_N / 128), 256, 0, stream>>>(hb, wqt, cosT, sinT, qb, kb, vt);
    // 3) fused causal attention, no K-split, direct normalized bf16 output
    flash_attn<<<dim3(256), 256, 0, stream>>>(qb, kb, vt, ab);
    // 4) out = attn @ w_o (64x128 tiles, 512 blocks)
    gemm_out<<<dim3(T / 64, HIDDEN / 128), 256, 0, stream>>>(ab, wot, out, Q_SIZE, HIDDEN);
}

// Round 12
// 233.678 us; speedup vs baseline: 1.1362x; 1.1362x over previous
//
#include <hip/hip_runtime.h>
#include <math.h>

#define T 2048
#define HIDDEN 2048
#define NH 16
#define NKV 4
#define HD 128
#define QKV_N 3072   // (16 + 2*4) * 128
#define Q_SIZE 2048  // 16*128
#define KV_SIZE 512  // 4*128

typedef __attribute__((ext_vector_type(8))) short short8;
typedef __attribute__((ext_vector_type(4))) short short4v;
typedef __attribute__((ext_vector_type(4))) float floatx4;

__device__ __forceinline__ unsigned short f2bf(float f) {
    union { float f; unsigned int u; } v; v.f = f;
    unsigned int u = v.u;
    u += 0x7fffu + ((u >> 16) & 1u);   // round-to-nearest-even
    return (unsigned short)(u >> 16);
}

// async global->LDS, 16B per lane; LDS dest = wave-uniform base + lane*16 (HW adds it)
__device__ __forceinline__ void gload_lds16(const unsigned short* g, unsigned short* l) {
    __builtin_amdgcn_global_load_lds((const __attribute__((address_space(1))) unsigned int*)g,
                                     (__attribute__((address_space(3))) unsigned int*)l, 16, 0, 0);
}

// ---------------- fused prep: convert hb + transpose wqt + transpose wot + cos/sin ----------------
__global__ __launch_bounds__(256) void prep_misc(const float* __restrict__ hidden,
                                                 const float* __restrict__ w_qkv,
                                                 const float* __restrict__ w_o,
                                                 const int* __restrict__ positions,
                                                 unsigned short* __restrict__ hb,
                                                 unsigned short* __restrict__ wqt,
                                                 unsigned short* __restrict__ wot,
                                                 float* __restrict__ cosT,
                                                 float* __restrict__ sinT) {
    __shared__ float tile[32][33];
    const int b = blockIdx.x;
    const int tid = threadIdx.x;
    const int tx = tid & 31, ty = tid >> 5;

    if (b < 4096) {
        int i = (b * 256 + tid) * 4;
        float4 v = *(const float4*)(hidden + i);
        hb[i]     = f2bf(v.x);
        hb[i + 1] = f2bf(v.y);
        hb[i + 2] = f2bf(v.z);
        hb[i + 3] = f2bf(v.w);
    } else if (b < 10240) {
        int idx = b - 4096;
        int c0 = (idx % 96) * 32, r0 = (idx / 96) * 32;
#pragma unroll
        for (int i = 0; i < 4; ++i)
            tile[ty + i * 8][tx] = w_qkv[(long)(r0 + ty + i * 8) * QKV_N + c0 + tx];
        __syncthreads();
#pragma unroll
        for (int i = 0; i < 4; ++i)
            wqt[(long)(c0 + ty + i * 8) * HIDDEN + r0 + tx] = f2bf(tile[tx][ty + i * 8]);
    } else if (b < 14336) {
        int idx = b - 10240;
        int c0 = (idx % 64) * 32, r0 = (idx / 64) * 32;
#pragma unroll
        for (int i = 0; i < 4; ++i)
            tile[ty + i * 8][tx] = w_o[(long)(r0 + ty + i * 8) * HIDDEN + c0 + tx];
        __syncthreads();
#pragma unroll
        for (int i = 0; i < 4; ++i)
            wot[(long)(c0 + ty + i * 8) * HIDDEN + r0 + tx] = f2bf(tile[tx][ty + i * 8]);
    } else {
        int idx = b - 14336;
        int t = idx * 4 + (tid >> 6);
        int j = tid & 63;
        int row = (j >= 44) ? 0 : ((j & 1) ? 2 : 1);
        int pos = positions[row * T + t];
        float invf = exp2f((float)j * -0.29580571f);   // log2(500000)/64
        float ang = (float)pos * invf;
        cosT[t * 64 + j] = cosf(ang);
        sinT[t * 64 + j] = sinf(ang);
    }
}

// ---------------- qkv GEMM: 64x128 tile (3 blocks/CU), dbuf async, rope fused ----------------
__global__ __launch_bounds__(256) void gemm_qkv(const unsigned short* __restrict__ A,
                                                const unsigned short* __restrict__ B,
                                                const float* __restrict__ cosT,
                                                const float* __restrict__ sinT,
                                                unsigned short* __restrict__ qb,
                                                unsigned short* __restrict__ kb,
                                                unsigned short* __restrict__ vt) {
    __shared__ __align__(16) unsigned short As[2][64 * 32];    // 2 x 4 KB
    __shared__ __align__(16) unsigned short Bs[2][128 * 32];   // 2 x 8 KB
    const int K = HIDDEN;
    const int tid = threadIdx.x;
    const int wv = tid >> 6;
    const int lane = tid & 63;
    const int m = lane & 15, qd = lane >> 4;
    const unsigned short* Ab = A + (long)(blockIdx.x * 64) * K;
    const unsigned short* Bb = B + (long)(blockIdx.y * 128) * K;
    const int srow = tid >> 2;          // 0..63
    const int scol = (tid & 3) * 8;

    floatx4 acc[4][2];
#pragma unroll
    for (int i = 0; i < 4; ++i)
#pragma unroll
        for (int j = 0; j < 2; ++j) acc[i][j] = (floatx4){0.f, 0.f, 0.f, 0.f};

#define QKV_STAGE(buf, k0)                                                                \
    do {                                                                                  \
        gload_lds16(Ab + (long)srow * K + (k0) + scol,        &As[buf][wv * 512]);        \
        gload_lds16(Bb + (long)srow * K + (k0) + scol,        &Bs[buf][wv * 512]);        \
        gload_lds16(Bb + (long)(64 + srow) * K + (k0) + scol, &Bs[buf][2048 + wv * 512]); \
    } while (0)

    QKV_STAGE(0, 0);
    int cur = 0;
    for (int k0 = 0; k0 < K; k0 += 32) {
        __syncthreads();                       // buf[cur] landed; prev readers of buf[cur^1] done
        if (k0 + 32 < K) QKV_STAGE(cur ^ 1, k0 + 32);
        short8 a[4], b[2];
#pragma unroll
        for (int i = 0; i < 4; ++i) a[i] = *(const short8*)&As[cur][(i * 16 + m) * 32 + qd * 8];
#pragma unroll
        for (int j = 0; j < 2; ++j) b[j] = *(const short8*)&Bs[cur][(wv * 32 + j * 16 + m) * 32 + qd * 8];
#pragma unroll
        for (int i = 0; i < 4; ++i)
#pragma unroll
            for (int j = 0; j < 2; ++j)
                acc[i][j] = __builtin_amdgcn_mfma_f32_16x16x32_bf16(a[i], b[j], acc[i][j], 0, 0, 0);
        cur ^= 1;
    }
#undef QKV_STAGE

    const int by = blockIdx.y;
    if (by < 20) {
        // rope path (q: by<16, k: 16..19); pairs are adjacent cols -> shfl_xor(val,1)
        const float sgn = (m & 1) ? 1.f : -1.f;
        const float qscale = 0.08838834764831845f;   // 1/sqrt(128)
#pragma unroll
        for (int i = 0; i < 4; ++i) {
#pragma unroll
            for (int r = 0; r < 4; ++r) {
                const int t = blockIdx.x * 64 + i * 16 + qd * 4 + r;
                const float* ct = cosT + t * 64;
                const float* st = sinT + t * 64;
#pragma unroll
                for (int j = 0; j < 2; ++j) {
                    const int cq = wv * 32 + j * 16 + m;
                    const int j2 = cq >> 1;
                    float val = acc[i][j][r];
                    float prt = __shfl_xor(val, 1);
                    float o = val * ct[j2] + sgn * prt * st[j2];
                    const int col = by * 128 + cq;
                    if (by < 16) qb[(long)t * Q_SIZE + col] = f2bf(o * qscale);
                    else         kb[(long)t * KV_SIZE + (col - 2048)] = f2bf(o);
                }
            }
        }
    } else {
        // v path: write V^T directly: vt[g][d][t]
        const int g = by - 20;
#pragma unroll
        for (int i = 0; i < 4; ++i)
#pragma unroll
            for (int j = 0; j < 2; ++j) {
                const int d = wv * 32 + j * 16 + m;
                const int t0 = blockIdx.x * 64 + i * 16 + qd * 4;
                unsigned short o4[4];
#pragma unroll
                for (int r = 0; r < 4; ++r) o4[r] = f2bf(acc[i][j][r]);
                *(short4v*)&vt[((long)g * HD + d) * T + t0] = *(short4v*)o4;
            }
    }
}

// ---------------- out GEMM: 64x128 tile (2 blocks/CU), dbuf async: C(fp32) = A * B^T ----------
__global__ __launch_bounds__(256) void gemm_out(const unsigned short* __restrict__ A,
                                                const unsigned short* __restrict__ B,
                                                float* __restrict__ C,
                                                int K, int ldc) {
    __shared__ __align__(16) unsigned short As[2][64 * 32];
    __shared__ __align__(16) unsigned short Bs[2][128 * 32];
    const int tid = threadIdx.x;
    const int wv = tid >> 6;
    const int lane = tid & 63;
    const int m = lane & 15, qd = lane >> 4;
    const unsigned short* Ab = A + (long)(blockIdx.x * 64) * K;
    const unsigned short* Bb = B + (long)(blockIdx.y * 128) * K;
    const int srow = tid >> 2;
    const int scol = (tid & 3) * 8;

    floatx4 acc[4][2];
#pragma unroll
    for (int i = 0; i < 4; ++i)
#pragma unroll
        for (int j = 0; j < 2; ++j) acc[i][j] = (floatx4){0.f, 0.f, 0.f, 0.f};

#define OUT_STAGE(buf, k0)                                                                \
    do {                                                                                  \
        gload_lds16(Ab + (long)srow * K + (k0) + scol,        &As[buf][wv * 512]);        \
        gload_lds16(Bb + (long)srow * K + (k0) + scol,        &Bs[buf][wv * 512]);        \
        gload_lds16(Bb + (long)(64 + srow) * K + (k0) + scol, &Bs[buf][2048 + wv * 512]); \
    } while (0)

    OUT_STAGE(0, 0);
    int cur = 0;
    for (int k0 = 0; k0 < K; k0 += 32) {
        __syncthreads();
        if (k0 + 32 < K) OUT_STAGE(cur ^ 1, k0 + 32);
        short8 a[4], b[2];
#pragma unroll
        for (int i = 0; i < 4; ++i) a[i] = *(const short8*)&As[cur][(i * 16 + m) * 32 + qd * 8];
#pragma unroll
        for (int j = 0; j < 2; ++j) b[j] = *(const short8*)&Bs[cur][(wv * 32 + j * 16 + m) * 32 + qd * 8];
#pragma unroll
        for (int i = 0; i < 4; ++i)
#pragma unroll
            for (int j = 0; j < 2; ++j)
                acc[i][j] = __builtin_amdgcn_mfma_f32_16x16x32_bf16(a[i], b[j], acc[i][j], 0, 0, 0);
        cur ^= 1;
    }
#undef OUT_STAGE

#pragma unroll
    for (int i = 0; i < 4; ++i)
#pragma unroll
        for (int j = 0; j < 2; ++j)
#pragma unroll
            for (int r = 0; r < 4; ++r)
                C[(long)(blockIdx.x * 64 + i * 16 + qd * 4 + r) * ldc +
                  blockIdx.y * 128 + wv * 32 + j * 16 + m] = acc[i][j][r];
}

// ---------------- flash attention v9: one (qt,half) unit per block, heavy/light CU pairing ----
// grid(512): bx = hi*256 + c, c = h*16 + j. hi=0 -> qt=15-(j>>1) (9..16 iters);
// hi=1 -> qt=j>>1 (1..8 iters); half = j&1. With CU ~ bx mod 256, each CU co-hosts one
// heavy + one light block of the SAME head: 17 iters total, 2 waves/SIMD overlap.
__global__ __launch_bounds__(256, 2) void flash_attn(const unsigned short* __restrict__ qb,
                                                     const unsigned short* __restrict__ kb,
                                                     const unsigned short* __restrict__ vt,
                                                     float* __restrict__ Opart,
                                                     float* __restrict__ MLpart) {
    __shared__ __align__(16) unsigned short Kbuf[2][64 * 128];   // 32 KB
    __shared__ __align__(16) unsigned short Vbuf[128 * 64];      // 16 KB
    __shared__ __align__(16) unsigned short Pls[4][32 * 72];     // 18.4 KB

    const int tid = threadIdx.x;
    const int wv = tid >> 6;
    const int lane = tid & 63;
    const int m = lane & 15;
    const int qd = lane >> 4;

    const int bx = blockIdx.x;
    const int c_ = bx & 255;
    const int hi = bx >> 8;
    const int h = c_ >> 4;
    const int j_ = c_ & 15;
    const int qt = hi ? (j_ >> 1) : (15 - (j_ >> 1));
    const int half = j_ & 1;
    const int g = h >> 2;
    unsigned short* myP = Pls[wv];

    const int n0 = qt + 1;
    const int jt0 = half ? n0 : 0;
    const int jt1 = half ? 2 * qt + 2 : n0;
    const int q0 = qt * 128;

    short8 aq[2][4];
#pragma unroll
    for (int s = 0; s < 2; ++s)
#pragma unroll
        for (int kk = 0; kk < 4; ++kk)
            aq[s][kk] = *(const short8*)(qb + (long)(q0 + s * 64 + wv * 16 + m) * Q_SIZE +
                                         h * HD + kk * 32 + qd * 8);

    floatx4 acc_o[2][8];
#pragma unroll
    for (int s = 0; s < 2; ++s)
#pragma unroll
        for (int nb = 0; nb < 8; ++nb) acc_o[s][nb] = (floatx4){0.f, 0.f, 0.f, 0.f};
    float mrow[2] = {-1e30f, -1e30f};
    float lrow[2] = {0.f, 0.f};

    // stage first K tile (XOR chunk swizzle c^(r&15))
#pragma unroll
    for (int i = 0; i < 4; ++i) {
        int s_ = i * 256 + tid;
        int r = s_ >> 4, c = (s_ & 15) ^ (r & 15);
        gload_lds16(kb + (long)(jt0 * 64 + r) * KV_SIZE + g * HD + c * 8,
                    &Kbuf[0][i * 2048 + wv * 512]);
    }
    int cur = 0;
    for (int jt = jt0; jt < jt1; ++jt) {
        __syncthreads();   // K[cur] landed; all prior LDS readers done

        if (jt + 1 < jt1) {   // K prefetch -> other buffer (full iter to land)
#pragma unroll
            for (int i = 0; i < 4; ++i) {
                int s_ = i * 256 + tid;
                int r = s_ >> 4, c = (s_ & 15) ^ (r & 15);
                gload_lds16(kb + (long)((jt + 1) * 64 + r) * KV_SIZE + g * HD + c * 8,
                            &Kbuf[cur ^ 1][i * 2048 + wv * 512]);
            }
        }
        // V for CURRENT tile (single buffer; consumed after mid barrier)
#pragma unroll
        for (int i = 0; i < 4; ++i) {
            int s_ = i * 256 + tid;
            int r = s_ >> 3, c = (s_ & 7) ^ (r & 7);
            gload_lds16(vt + ((long)g * HD + r) * T + jt * 64 + c * 8,
                        &Vbuf[i * 2048 + wv * 512]);
        }

        // S^T = K Q^T for both q-sets, sharing K fragment loads
        floatx4 acc_s[2][4];
#pragma unroll
        for (int s = 0; s < 2; ++s)
#pragma unroll
            for (int c = 0; c < 4; ++c) acc_s[s][c] = (floatx4){0.f, 0.f, 0.f, 0.f};
#pragma unroll
        for (int kk = 0; kk < 4; ++kk) {
#pragma unroll
            for (int c = 0; c < 4; ++c) {
                short8 ak = *(const short8*)&Kbuf[cur][(c * 16 + m) * 128 +
                                                       (((4 * kk + qd) ^ m) * 8)];
                acc_s[0][c] = __builtin_amdgcn_mfma_f32_16x16x32_bf16(ak, aq[0][kk], acc_s[0][c], 0, 0, 0);
                acc_s[1][c] = __builtin_amdgcn_mfma_f32_16x16x32_bf16(ak, aq[1][kk], acc_s[1][c], 0, 0, 0);
            }
        }

        // per-set online softmax + P write
#pragma unroll
        for (int s = 0; s < 2; ++s) {
            const int dg = 2 * qt + s;
            if (jt >= dg) {
                const bool full = (jt > dg);
#pragma unroll
                for (int c = 0; c < 4; ++c)
#pragma unroll
                    for (int r = 0; r < 4; ++r)
                        if (full || (c * 16 + qd * 4 + r > wv * 16 + m)) acc_s[s][c][r] = -1e30f;
            }
            float mx = acc_s[s][0][0];
#pragma unroll
            for (int c = 0; c < 4; ++c)
#pragma unroll
                for (int r = 0; r < 4; ++r) mx = fmaxf(mx, acc_s[s][c][r]);
            mx = fmaxf(mx, __shfl_xor(mx, 16));
            mx = fmaxf(mx, __shfl_xor(mx, 32));
            float mnew = fmaxf(mrow[s], mx);
            float alpha = __expf(mrow[s] - mnew);
            mrow[s] = mnew;

            float pv[4][4];
            float lsum = 0.f;
#pragma unroll
            for (int c = 0; c < 4; ++c)
#pragma unroll
                for (int r = 0; r < 4; ++r) {
                    pv[c][r] = __expf(acc_s[s][c][r] - mnew);
                    lsum += pv[c][r];
                }
            lsum += __shfl_xor(lsum, 16);
            lsum += __shfl_xor(lsum, 32);
            lrow[s] = lrow[s] * alpha + lsum;
#pragma unroll
            for (int nb = 0; nb < 8; ++nb)
#pragma unroll
                for (int r = 0; r < 4; ++r) acc_o[s][nb][r] *= alpha;
#pragma unroll
            for (int c = 0; c < 4; ++c) {
                short4v pk = {(short)f2bf(pv[c][0]), (short)f2bf(pv[c][1]),
                              (short)f2bf(pv[c][2]), (short)f2bf(pv[c][3])};
                *(short4v*)&myP[(s * 16 + m) * 72 + c * 16 + qd * 4] = pk;
            }
        }

        __syncthreads();   // V landed (and block-wide sync)

        // PV for both sets, sharing V fragment loads
#pragma unroll
        for (int kk = 0; kk < 2; ++kk) {
            short8 pa0 = *(const short8*)&myP[m * 72 + kk * 32 + qd * 8];
            short8 pa1 = *(const short8*)&myP[(16 + m) * 72 + kk * 32 + qd * 8];
#pragma unroll
            for (int nb = 0; nb < 8; ++nb) {
                short8 av = *(const short8*)&Vbuf[(nb * 16 + m) * 64 +
                                                  (((4 * kk + qd) ^ (m & 7)) * 8)];
                acc_o[0][nb] = __builtin_amdgcn_mfma_f32_16x16x32_bf16(av, pa0, acc_o[0][nb], 0, 0, 0);
                acc_o[1][nb] = __builtin_amdgcn_mfma_f32_16x16x32_bf16(av, pa1, acc_o[1][nb], 0, 0, 0);
            }
        }
        cur ^= 1;
    }

    // store partials for this unit
    const int unit = (h * 16 + qt) * 2 + half;
#pragma unroll
    for (int s = 0; s < 2; ++s) {
        const long rb = (long)unit * 128 + s * 64 + wv * 16 + m;
#pragma unroll
        for (int nb = 0; nb < 8; ++nb)
            *(floatx4*)&Opart[rb * 128 + nb * 16 + qd * 4] = acc_o[s][nb];
        if (qd == 0) {
            MLpart[rb * 2]     = mrow[s];
            MLpart[rb * 2 + 1] = lrow[s];
        }
    }
}

// ---------------- combine K-split partials -> ab bf16 [t][h*128+d] ----------------
__global__ __launch_bounds__(256) void attn_combine(const float* __restrict__ Opart,
                                                    const float* __restrict__ MLpart,
                                                    unsigned short* __restrict__ ab) {
    const int tid = threadIdx.x;
    const int q = blockIdx.x * 16 + (tid >> 4);
    const int h = blockIdx.y;
    const int d0 = (tid & 15) * 8;
    const int qt = q >> 7, lr = q & 127;
    const long r0 = ((long)(h * 16 + qt) * 2) * 128 + lr;
    const long r1 = r0 + 128;
    float m0 = MLpart[r0 * 2], l0 = MLpart[r0 * 2 + 1];
    float m1 = MLpart[r1 * 2], l1 = MLpart[r1 * 2 + 1];
    float M = fmaxf(m0, m1);
    float a0 = __expf(m0 - M), a1 = __expf(m1 - M);
    float inv = 1.f / (l0 * a0 + l1 * a1);
    const float* O0 = Opart + r0 * 128 + d0;
    const float* O1 = Opart + r1 * 128 + d0;
    unsigned short outv[8];
#pragma unroll
    for (int j = 0; j < 8; j += 4) {
        float4 x0 = *(const float4*)(O0 + j);
        float4 x1 = *(const float4*)(O1 + j);
        outv[j]     = f2bf((x0.x * a0 + x1.x * a1) * inv);
        outv[j + 1] = f2bf((x0.y * a0 + x1.y * a1) * inv);
        outv[j + 2] = f2bf((x0.z * a0 + x1.z * a1) * inv);
        outv[j + 3] = f2bf((x0.w * a0 + x1.w * a1) * inv);
    }
    *(short8*)&ab[(long)q * Q_SIZE + h * HD + d0] = *(short8*)outv;
}

extern "C" void kernel_launch(void* const* d_in, const int* in_sizes, int n_in,
                              void* d_out, int out_size, void* d_ws, size_t ws_size,
                              hipStream_t stream) {
    const int* positions = (const int*)d_in[0];
    const float* hidden  = (const float*)d_in[1];
    const float* w_qkv   = (const float*)d_in[2];
    const float* w_o     = (const float*)d_in[3];
    float* out = (float*)d_out;

    char* p = (char*)d_ws;
    auto alloc = [&](size_t bytes) { char* r = p; p += (bytes + 255) & ~(size_t)255; return r; };
    float* cosT = (float*)alloc((size_t)T * 64 * 4);
    float* sinT = (float*)alloc((size_t)T * 64 * 4);
    unsigned short* hb  = (unsigned short*)alloc((size_t)T * HIDDEN * 2);
    unsigned short* wqt = (unsigned short*)alloc((size_t)QKV_N * HIDDEN * 2);
    unsigned short* wot = (unsigned short*)alloc((size_t)HIDDEN * HIDDEN * 2);
    unsigned short* qb  = (unsigned short*)alloc((size_t)T * Q_SIZE * 2);
    unsigned short* kb  = (unsigned short*)alloc((size_t)T * KV_SIZE * 2);
    unsigned short* vt  = (unsigned short*)alloc((size_t)T * KV_SIZE * 2);
    unsigned short* ab  = (unsigned short*)alloc((size_t)T * Q_SIZE * 2);
    float* Opart  = (float*)alloc((size_t)512 * 128 * 128 * 4);   // 33.5 MB
    float* MLpart = (float*)alloc((size_t)512 * 128 * 2 * 4);

    // 1) fused prep (convert + 2 transposes + cos/sin tables)
    prep_misc<<<dim3(14848), 256, 0, stream>>>(hidden, w_qkv, w_o, positions,
                                               hb, wqt, wot, cosT, sinT);
    // 2) fused qkv projection + rope -> qb (scaled), kb, vt
    gemm_qkv<<<dim3(T / 64, QKV_N / 128), 256, 0, stream>>>(hb, wqt, cosT, sinT, qb, kb, vt);
    // 3) fused causal attention, 512 single-unit blocks, heavy+light per CU
    flash_attn<<<dim3(512), 256, 0, stream>>>(qb, kb, vt, Opart, MLpart);
    // 4) combine partials
    attn_combine<<<dim3(T / 16, NH), 256, 0, stream>>>(Opart, MLpart, ab);
    // 5) out = attn @ w_o
    gemm_out<<<dim3(T / 64, HIDDEN / 128), 256, 0, stream>>>(ab, wot, out, Q_SIZE, HIDDEN);
}

// Round 13
// 233.048 us; speedup vs baseline: 1.1393x; 1.0027x over previous
//
#include <hip/hip_runtime.h>
#include <math.h>

#define T 2048
#define HIDDEN 2048
#define NH 16
#define NKV 4
#define HD 128
#define QKV_N 3072   // (16 + 2*4) * 128
#define Q_SIZE 2048  // 16*128
#define KV_SIZE 512  // 4*128

typedef __attribute__((ext_vector_type(8))) short short8;
typedef __attribute__((ext_vector_type(4))) short short4v;
typedef __attribute__((ext_vector_type(4))) float floatx4;

__device__ __forceinline__ unsigned short f2bf(float f) {
    union { float f; unsigned int u; } v; v.f = f;
    unsigned int u = v.u;
    u += 0x7fffu + ((u >> 16) & 1u);   // round-to-nearest-even
    return (unsigned short)(u >> 16);
}

// async global->LDS, 16B per lane; LDS dest = wave-uniform base + lane*16 (HW adds it)
__device__ __forceinline__ void gload_lds16(const unsigned short* g, unsigned short* l) {
    __builtin_amdgcn_global_load_lds((const __attribute__((address_space(1))) unsigned int*)g,
                                     (__attribute__((address_space(3))) unsigned int*)l, 16, 0, 0);
}

// ---------------- fused prep: convert hb + transpose wqt + transpose wot + cos/sin ----------------
__global__ __launch_bounds__(256) void prep_misc(const float* __restrict__ hidden,
                                                 const float* __restrict__ w_qkv,
                                                 const float* __restrict__ w_o,
                                                 const int* __restrict__ positions,
                                                 unsigned short* __restrict__ hb,
                                                 unsigned short* __restrict__ wqt,
                                                 unsigned short* __restrict__ wot,
                                                 float* __restrict__ cosT,
                                                 float* __restrict__ sinT) {
    __shared__ float tile[32][33];
    const int b = blockIdx.x;
    const int tid = threadIdx.x;
    const int tx = tid & 31, ty = tid >> 5;

    if (b < 4096) {
        int i = (b * 256 + tid) * 4;
        float4 v = *(const float4*)(hidden + i);
        hb[i]     = f2bf(v.x);
        hb[i + 1] = f2bf(v.y);
        hb[i + 2] = f2bf(v.z);
        hb[i + 3] = f2bf(v.w);
    } else if (b < 10240) {
        int idx = b - 4096;
        int c0 = (idx % 96) * 32, r0 = (idx / 96) * 32;
#pragma unroll
        for (int i = 0; i < 4; ++i)
            tile[ty + i * 8][tx] = w_qkv[(long)(r0 + ty + i * 8) * QKV_N + c0 + tx];
        __syncthreads();
#pragma unroll
        for (int i = 0; i < 4; ++i)
            wqt[(long)(c0 + ty + i * 8) * HIDDEN + r0 + tx] = f2bf(tile[tx][ty + i * 8]);
    } else if (b < 14336) {
        int idx = b - 10240;
        int c0 = (idx % 64) * 32, r0 = (idx / 64) * 32;
#pragma unroll
        for (int i = 0; i < 4; ++i)
            tile[ty + i * 8][tx] = w_o[(long)(r0 + ty + i * 8) * HIDDEN + c0 + tx];
        __syncthreads();
#pragma unroll
        for (int i = 0; i < 4; ++i)
            wot[(long)(c0 + ty + i * 8) * HIDDEN + r0 + tx] = f2bf(tile[tx][ty + i * 8]);
    } else {
        int idx = b - 14336;
        int t = idx * 4 + (tid >> 6);
        int j = tid & 63;
        int row = (j >= 44) ? 0 : ((j & 1) ? 2 : 1);
        int pos = positions[row * T + t];
        float invf = exp2f((float)j * -0.29580571f);   // log2(500000)/64
        float ang = (float)pos * invf;
        cosT[t * 64 + j] = cosf(ang);
        sinT[t * 64 + j] = sinf(ang);
    }
}

// ---------------- qkv GEMM: 64x128 tile, dbuf async, XOR-swizzled LDS, rope fused ----------------
// LDS tiles stored with chunk swizzle: 16B chunk c of row r lives at slot c^(r&3).
// Staging fetches global chunk (tid&3)^(srow&3); reads use chunk qd^(m&3) ->
// bank group (m&1)*16 + (qd^(m&3))*4 = 8 lanes per 4-bank group (conflict-minimal b128).
__global__ __launch_bounds__(256) void gemm_qkv(const unsigned short* __restrict__ A,
                                                const unsigned short* __restrict__ B,
                                                const float* __restrict__ cosT,
                                                const float* __restrict__ sinT,
                                                unsigned short* __restrict__ qb,
                                                unsigned short* __restrict__ kb,
                                                unsigned short* __restrict__ vt) {
    __shared__ __align__(16) unsigned short As[2][64 * 32];    // 2 x 4 KB
    __shared__ __align__(16) unsigned short Bs[2][128 * 32];   // 2 x 8 KB
    const int K = HIDDEN;
    const int tid = threadIdx.x;
    const int wv = tid >> 6;
    const int lane = tid & 63;
    const int m = lane & 15, qd = lane >> 4;
    const unsigned short* Ab = A + (long)(blockIdx.x * 64) * K;
    const unsigned short* Bb = B + (long)(blockIdx.y * 128) * K;
    const int srow = tid >> 2;          // 0..63
    const int scol = (((tid & 3) ^ (srow & 3)) * 8);   // XOR-swizzled source chunk
    const int rch = (qd ^ (m & 3)) * 8;                // XOR-swizzled read chunk

    floatx4 acc[4][2];
#pragma unroll
    for (int i = 0; i < 4; ++i)
#pragma unroll
        for (int j = 0; j < 2; ++j) acc[i][j] = (floatx4){0.f, 0.f, 0.f, 0.f};

#define QKV_STAGE(buf, k0)                                                                \
    do {                                                                                  \
        gload_lds16(Ab + (long)srow * K + (k0) + scol,        &As[buf][wv * 512]);        \
        gload_lds16(Bb + (long)srow * K + (k0) + scol,        &Bs[buf][wv * 512]);        \
        gload_lds16(Bb + (long)(64 + srow) * K + (k0) + scol, &Bs[buf][2048 + wv * 512]); \
    } while (0)

    QKV_STAGE(0, 0);
    int cur = 0;
    for (int k0 = 0; k0 < K; k0 += 32) {
        __syncthreads();                       // buf[cur] landed; prev readers of buf[cur^1] done
        if (k0 + 32 < K) QKV_STAGE(cur ^ 1, k0 + 32);
        short8 a[4], b[2];
#pragma unroll
        for (int i = 0; i < 4; ++i) a[i] = *(const short8*)&As[cur][(i * 16 + m) * 32 + rch];
#pragma unroll
        for (int j = 0; j < 2; ++j) b[j] = *(const short8*)&Bs[cur][(wv * 32 + j * 16 + m) * 32 + rch];
#pragma unroll
        for (int i = 0; i < 4; ++i)
#pragma unroll
            for (int j = 0; j < 2; ++j)
                acc[i][j] = __builtin_amdgcn_mfma_f32_16x16x32_bf16(a[i], b[j], acc[i][j], 0, 0, 0);
        cur ^= 1;
    }
#undef QKV_STAGE

    const int by = blockIdx.y;
    if (by < 20) {
        // rope path (q: by<16, k: 16..19); pairs are adjacent cols -> shfl_xor(val,1)
        const float sgn = (m & 1) ? 1.f : -1.f;
        const float qscale = 0.08838834764831845f;   // 1/sqrt(128)
#pragma unroll
        for (int i = 0; i < 4; ++i) {
#pragma unroll
            for (int r = 0; r < 4; ++r) {
                const int t = blockIdx.x * 64 + i * 16 + qd * 4 + r;
                const float* ct = cosT + t * 64;
                const float* st = sinT + t * 64;
#pragma unroll
                for (int j = 0; j < 2; ++j) {
                    const int cq = wv * 32 + j * 16 + m;
                    const int j2 = cq >> 1;
                    float val = acc[i][j][r];
                    float prt = __shfl_xor(val, 1);
                    float o = val * ct[j2] + sgn * prt * st[j2];
                    const int col = by * 128 + cq;
                    if (by < 16) qb[(long)t * Q_SIZE + col] = f2bf(o * qscale);
                    else         kb[(long)t * KV_SIZE + (col - 2048)] = f2bf(o);
                }
            }
        }
    } else {
        // v path: write V^T directly: vt[g][d][t]
        const int g = by - 20;
#pragma unroll
        for (int i = 0; i < 4; ++i)
#pragma unroll
            for (int j = 0; j < 2; ++j) {
                const int d = wv * 32 + j * 16 + m;
                const int t0 = blockIdx.x * 64 + i * 16 + qd * 4;
                unsigned short o4[4];
#pragma unroll
                for (int r = 0; r < 4; ++r) o4[r] = f2bf(acc[i][j][r]);
                *(short4v*)&vt[((long)g * HD + d) * T + t0] = *(short4v*)o4;
            }
    }
}

// ---------------- out GEMM: 64x128 tile, dbuf async, XOR-swizzled LDS: C(fp32) = A * B^T ------
__global__ __launch_bounds__(256) void gemm_out(const unsigned short* __restrict__ A,
                                                const unsigned short* __restrict__ B,
                                                float* __restrict__ C,
                                                int K, int ldc) {
    __shared__ __align__(16) unsigned short As[2][64 * 32];
    __shared__ __align__(16) unsigned short Bs[2][128 * 32];
    const int tid = threadIdx.x;
    const int wv = tid >> 6;
    const int lane = tid & 63;
    const int m = lane & 15, qd = lane >> 4;
    const unsigned short* Ab = A + (long)(blockIdx.x * 64) * K;
    const unsigned short* Bb = B + (long)(blockIdx.y * 128) * K;
    const int srow = tid >> 2;
    const int scol = (((tid & 3) ^ (srow & 3)) * 8);   // XOR-swizzled source chunk
    const int rch = (qd ^ (m & 3)) * 8;                // XOR-swizzled read chunk

    floatx4 acc[4][2];
#pragma unroll
    for (int i = 0; i < 4; ++i)
#pragma unroll
        for (int j = 0; j < 2; ++j) acc[i][j] = (floatx4){0.f, 0.f, 0.f, 0.f};

#define OUT_STAGE(buf, k0)                                                                \
    do {                                                                                  \
        gload_lds16(Ab + (long)srow * K + (k0) + scol,        &As[buf][wv * 512]);        \
        gload_lds16(Bb + (long)srow * K + (k0) + scol,        &Bs[buf][wv * 512]);        \
        gload_lds16(Bb + (long)(64 + srow) * K + (k0) + scol, &Bs[buf][2048 + wv * 512]); \
    } while (0)

    OUT_STAGE(0, 0);
    int cur = 0;
    for (int k0 = 0; k0 < K; k0 += 32) {
        __syncthreads();
        if (k0 + 32 < K) OUT_STAGE(cur ^ 1, k0 + 32);
        short8 a[4], b[2];
#pragma unroll
        for (int i = 0; i < 4; ++i) a[i] = *(const short8*)&As[cur][(i * 16 + m) * 32 + rch];
#pragma unroll
        for (int j = 0; j < 2; ++j) b[j] = *(const short8*)&Bs[cur][(wv * 32 + j * 16 + m) * 32 + rch];
#pragma unroll
        for (int i = 0; i < 4; ++i)
#pragma unroll
            for (int j = 0; j < 2; ++j)
                acc[i][j] = __builtin_amdgcn_mfma_f32_16x16x32_bf16(a[i], b[j], acc[i][j], 0, 0, 0);
        cur ^= 1;
    }
#undef OUT_STAGE

#pragma unroll
    for (int i = 0; i < 4; ++i)
#pragma unroll
        for (int j = 0; j < 2; ++j)
#pragma unroll
            for (int r = 0; r < 4; ++r)
                C[(long)(blockIdx.x * 64 + i * 16 + qd * 4 + r) * ldc +
                  blockIdx.y * 128 + wv * 32 + j * 16 + m] = acc[i][j][r];
}

// ---------------- flash attention v9: one (qt,half) unit per block, heavy/light CU pairing ----
__global__ __launch_bounds__(256, 2) void flash_attn(const unsigned short* __restrict__ qb,
                                                     const unsigned short* __restrict__ kb,
                                                     const unsigned short* __restrict__ vt,
                                                     float* __restrict__ Opart,
                                                     float* __restrict__ MLpart) {
    __shared__ __align__(16) unsigned short Kbuf[2][64 * 128];   // 32 KB
    __shared__ __align__(16) unsigned short Vbuf[128 * 64];      // 16 KB
    __shared__ __align__(16) unsigned short Pls[4][32 * 72];     // 18.4 KB

    const int tid = threadIdx.x;
    const int wv = tid >> 6;
    const int lane = tid & 63;
    const int m = lane & 15;
    const int qd = lane >> 4;

    const int bx = blockIdx.x;
    const int c_ = bx & 255;
    const int hi = bx >> 8;
    const int h = c_ >> 4;
    const int j_ = c_ & 15;
    const int qt = hi ? (j_ >> 1) : (15 - (j_ >> 1));
    const int half = j_ & 1;
    const int g = h >> 2;
    unsigned short* myP = Pls[wv];

    const int n0 = qt + 1;
    const int jt0 = half ? n0 : 0;
    const int jt1 = half ? 2 * qt + 2 : n0;
    const int q0 = qt * 128;

    short8 aq[2][4];
#pragma unroll
    for (int s = 0; s < 2; ++s)
#pragma unroll
        for (int kk = 0; kk < 4; ++kk)
            aq[s][kk] = *(const short8*)(qb + (long)(q0 + s * 64 + wv * 16 + m) * Q_SIZE +
                                         h * HD + kk * 32 + qd * 8);

    floatx4 acc_o[2][8];
#pragma unroll
    for (int s = 0; s < 2; ++s)
#pragma unroll
        for (int nb = 0; nb < 8; ++nb) acc_o[s][nb] = (floatx4){0.f, 0.f, 0.f, 0.f};
    float mrow[2] = {-1e30f, -1e30f};
    float lrow[2] = {0.f, 0.f};

    // stage first K tile (XOR chunk swizzle c^(r&15))
#pragma unroll
    for (int i = 0; i < 4; ++i) {
        int s_ = i * 256 + tid;
        int r = s_ >> 4, c = (s_ & 15) ^ (r & 15);
        gload_lds16(kb + (long)(jt0 * 64 + r) * KV_SIZE + g * HD + c * 8,
                    &Kbuf[0][i * 2048 + wv * 512]);
    }
    int cur = 0;
    for (int jt = jt0; jt < jt1; ++jt) {
        __syncthreads();   // K[cur] landed; all prior LDS readers done

        if (jt + 1 < jt1) {   // K prefetch -> other buffer (full iter to land)
#pragma unroll
            for (int i = 0; i < 4; ++i) {
                int s_ = i * 256 + tid;
                int r = s_ >> 4, c = (s_ & 15) ^ (r & 15);
                gload_lds16(kb + (long)((jt + 1) * 64 + r) * KV_SIZE + g * HD + c * 8,
                            &Kbuf[cur ^ 1][i * 2048 + wv * 512]);
            }
        }
        // V for CURRENT tile (single buffer; consumed after mid barrier)
#pragma unroll
        for (int i = 0; i < 4; ++i) {
            int s_ = i * 256 + tid;
            int r = s_ >> 3, c = (s_ & 7) ^ (r & 7);
            gload_lds16(vt + ((long)g * HD + r) * T + jt * 64 + c * 8,
                        &Vbuf[i * 2048 + wv * 512]);
        }

        // S^T = K Q^T for both q-sets, sharing K fragment loads
        floatx4 acc_s[2][4];
#pragma unroll
        for (int s = 0; s < 2; ++s)
#pragma unroll
            for (int c = 0; c < 4; ++c) acc_s[s][c] = (floatx4){0.f, 0.f, 0.f, 0.f};
#pragma unroll
        for (int kk = 0; kk < 4; ++kk) {
#pragma unroll
            for (int c = 0; c < 4; ++c) {
                short8 ak = *(const short8*)&Kbuf[cur][(c * 16 + m) * 128 +
                                                       (((4 * kk + qd) ^ m) * 8)];
                acc_s[0][c] = __builtin_amdgcn_mfma_f32_16x16x32_bf16(ak, aq[0][kk], acc_s[0][c], 0, 0, 0);
                acc_s[1][c] = __builtin_amdgcn_mfma_f32_16x16x32_bf16(ak, aq[1][kk], acc_s[1][c], 0, 0, 0);
            }
        }

        // per-set online softmax + P write
#pragma unroll
        for (int s = 0; s < 2; ++s) {
            const int dg = 2 * qt + s;
            if (jt >= dg) {
                const bool full = (jt > dg);
#pragma unroll
                for (int c = 0; c < 4; ++c)
#pragma unroll
                    for (int r = 0; r < 4; ++r)
                        if (full || (c * 16 + qd * 4 + r > wv * 16 + m)) acc_s[s][c][r] = -1e30f;
            }
            float mx = acc_s[s][0][0];
#pragma unroll
            for (int c = 0; c < 4; ++c)
#pragma unroll
                for (int r = 0; r < 4; ++r) mx = fmaxf(mx, acc_s[s][c][r]);
            mx = fmaxf(mx, __shfl_xor(mx, 16));
            mx = fmaxf(mx, __shfl_xor(mx, 32));
            float mnew = fmaxf(mrow[s], mx);
            float alpha = __expf(mrow[s] - mnew);
            mrow[s] = mnew;

            float pv[4][4];
            float lsum = 0.f;
#pragma unroll
            for (int c = 0; c < 4; ++c)
#pragma unroll
                for (int r = 0; r < 4; ++r) {
                    pv[c][r] = __expf(acc_s[s][c][r] - mnew);
                    lsum += pv[c][r];
                }
            lsum += __shfl_xor(lsum, 16);
            lsum += __shfl_xor(lsum, 32);
            lrow[s] = lrow[s] * alpha + lsum;
#pragma unroll
            for (int nb = 0; nb < 8; ++nb)
#pragma unroll
                for (int r = 0; r < 4; ++r) acc_o[s][nb][r] *= alpha;
#pragma unroll
            for (int c = 0; c < 4; ++c) {
                short4v pk = {(short)f2bf(pv[c][0]), (short)f2bf(pv[c][1]),
                              (short)f2bf(pv[c][2]), (short)f2bf(pv[c][3])};
                *(short4v*)&myP[(s * 16 + m) * 72 + c * 16 + qd * 4] = pk;
            }
        }

        __syncthreads();   // V landed (and block-wide sync)

        // PV for both sets, sharing V fragment loads
#pragma unroll
        for (int kk = 0; kk < 2; ++kk) {
            short8 pa0 = *(const short8*)&myP[m * 72 + kk * 32 + qd * 8];
            short8 pa1 = *(const short8*)&myP[(16 + m) * 72 + kk * 32 + qd * 8];
#pragma unroll
            for (int nb = 0; nb < 8; ++nb) {
                short8 av = *(const short8*)&Vbuf[(nb * 16 + m) * 64 +
                                                  (((4 * kk + qd) ^ (m & 7)) * 8)];
                acc_o[0][nb] = __builtin_amdgcn_mfma_f32_16x16x32_bf16(av, pa0, acc_o[0][nb], 0, 0, 0);
                acc_o[1][nb] = __builtin_amdgcn_mfma_f32_16x16x32_bf16(av, pa1, acc_o[1][nb], 0, 0, 0);
            }
        }
        cur ^= 1;
    }

    // store partials for this unit
    const int unit = (h * 16 + qt) * 2 + half;
#pragma unroll
    for (int s = 0; s < 2; ++s) {
        const long rb = (long)unit * 128 + s * 64 + wv * 16 + m;
#pragma unroll
        for (int nb = 0; nb < 8; ++nb)
            *(floatx4*)&Opart[rb * 128 + nb * 16 + qd * 4] = acc_o[s][nb];
        if (qd == 0) {
            MLpart[rb * 2]     = mrow[s];
            MLpart[rb * 2 + 1] = lrow[s];
        }
    }
}

// ---------------- combine K-split partials -> ab bf16 [t][h*128+d] ----------------
__global__ __launch_bounds__(256) void attn_combine(const float* __restrict__ Opart,
                                                    const float* __restrict__ MLpart,
                                                    unsigned short* __restrict__ ab) {
    const int tid = threadIdx.x;
    const int q = blockIdx.x * 16 + (tid >> 4);
    const int h = blockIdx.y;
    const int d0 = (tid & 15) * 8;
    const int qt = q >> 7, lr = q & 127;
    const long r0 = ((long)(h * 16 + qt) * 2) * 128 + lr;
    const long r1 = r0 + 128;
    float m0 = MLpart[r0 * 2], l0 = MLpart[r0 * 2 + 1];
    float m1 = MLpart[r1 * 2], l1 = MLpart[r1 * 2 + 1];
    float M = fmaxf(m0, m1);
    float a0 = __expf(m0 - M), a1 = __expf(m1 - M);
    float inv = 1.f / (l0 * a0 + l1 * a1);
    const float* O0 = Opart + r0 * 128 + d0;
    const float* O1 = Opart + r1 * 128 + d0;
    unsigned short outv[8];
#pragma unroll
    for (int j = 0; j < 8; j += 4) {
        float4 x0 = *(const float4*)(O0 + j);
        float4 x1 = *(const float4*)(O1 + j);
        outv[j]     = f2bf((x0.x * a0 + x1.x * a1) * inv);
        outv[j + 1] = f2bf((x0.y * a0 + x1.y * a1) * inv);
        outv[j + 2] = f2bf((x0.z * a0 + x1.z * a1) * inv);
        outv[j + 3] = f2bf((x0.w * a0 + x1.w * a1) * inv);
    }
    *(short8*)&ab[(long)q * Q_SIZE + h * HD + d0] = *(short8*)outv;
}

extern "C" void kernel_launch(void* const* d_in, const int* in_sizes, int n_in,
                              void* d_out, int out_size, void* d_ws, size_t ws_size,
                              hipStream_t stream) {
    const int* positions = (const int*)d_in[0];
    const float* hidden  = (const float*)d_in[1];
    const float* w_qkv   = (const float*)d_in[2];
    const float* w_o     = (const float*)d_in[3];
    float* out = (float*)d_out;

    char* p = (char*)d_ws;
    auto alloc = [&](size_t bytes) { char* r = p; p += (bytes + 255) & ~(size_t)255; return r; };
    float* cosT = (float*)alloc((size_t)T * 64 * 4);
    float* sinT = (float*)alloc((size_t)T * 64 * 4);
    unsigned short* hb  = (unsigned short*)alloc((size_t)T * HIDDEN * 2);
    unsigned short* wqt = (unsigned short*)alloc((size_t)QKV_N * HIDDEN * 2);
    unsigned short* wot = (unsigned short*)alloc((size_t)HIDDEN * HIDDEN * 2);
    unsigned short* qb  = (unsigned short*)alloc((size_t)T * Q_SIZE * 2);
    unsigned short* kb  = (unsigned short*)alloc((size_t)T * KV_SIZE * 2);
    unsigned short* vt  = (unsigned short*)alloc((size_t)T * KV_SIZE * 2);
    unsigned short* ab  = (unsigned short*)alloc((size_t)T * Q_SIZE * 2);
    float* Opart  = (float*)alloc((size_t)512 * 128 * 128 * 4);   // 33.5 MB
    float* MLpart = (float*)alloc((size_t)512 * 128 * 2 * 4);

    // 1) fused prep (convert + 2 transposes + cos/sin tables)
    prep_misc<<<dim3(14848), 256, 0, stream>>>(hidden, w_qkv, w_o, positions,
                                               hb, wqt, wot, cosT, sinT);
    // 2) fused qkv projection + rope -> qb (scaled), kb, vt
    gemm_qkv<<<dim3(T / 64, QKV_N / 128), 256, 0, stream>>>(hb, wqt, cosT, sinT, qb, kb, vt);
    // 3) fused causal attention, 512 single-unit blocks, heavy+light per CU
    flash_attn<<<dim3(512), 256, 0, stream>>>(qb, kb, vt, Opart, MLpart);
    // 4) combine partials
    attn_combine<<<dim3(T / 16, NH), 256, 0, stream>>>(Opart, MLpart, ab);
    // 5) out = attn @ w_o
    gemm_out<<<dim3(T / 64, HIDDEN / 128), 256, 0, stream>>>(ab, wot, out, Q_SIZE, HIDDEN);
}

// Round 14
// 220.350 us; speedup vs baseline: 1.2050x; 1.0576x over previous
//
#include <hip/hip_runtime.h>
#include <math.h>

#define T 2048
#define HIDDEN 2048
#define NH 16
#define NKV 4
#define HD 128
#define QKV_N 3072   // (16 + 2*4) * 128
#define Q_SIZE 2048  // 16*128
#define KV_SIZE 512  // 4*128

typedef __attribute__((ext_vector_type(8))) short short8;
typedef __attribute__((ext_vector_type(4))) short short4v;
typedef __attribute__((ext_vector_type(4))) float floatx4;

__device__ __forceinline__ unsigned short f2bf(float f) {
    union { float f; unsigned int u; } v; v.f = f;
    unsigned int u = v.u;
    u += 0x7fffu + ((u >> 16) & 1u);   // round-to-nearest-even
    return (unsigned short)(u >> 16);
}

// async global->LDS, 16B per lane; LDS dest = wave-uniform base + lane*16 (HW adds it)
__device__ __forceinline__ void gload_lds16(const unsigned short* g, unsigned short* l) {
    __builtin_amdgcn_global_load_lds((const __attribute__((address_space(1))) unsigned int*)g,
                                     (__attribute__((address_space(3))) unsigned int*)l, 16, 0, 0);
}

// ---------------- fused prep: convert hb + transpose wqt + transpose wot + cos/sin ----------------
__global__ __launch_bounds__(256) void prep_misc(const float* __restrict__ hidden,
                                                 const float* __restrict__ w_qkv,
                                                 const float* __restrict__ w_o,
                                                 const int* __restrict__ positions,
                                                 unsigned short* __restrict__ hb,
                                                 unsigned short* __restrict__ wqt,
                                                 unsigned short* __restrict__ wot,
                                                 float* __restrict__ cosT,
                                                 float* __restrict__ sinT) {
    __shared__ float tile[32][33];
    const int b = blockIdx.x;
    const int tid = threadIdx.x;
    const int tx = tid & 31, ty = tid >> 5;

    if (b < 4096) {
        int i = (b * 256 + tid) * 4;
        float4 v = *(const float4*)(hidden + i);
        hb[i]     = f2bf(v.x);
        hb[i + 1] = f2bf(v.y);
        hb[i + 2] = f2bf(v.z);
        hb[i + 3] = f2bf(v.w);
    } else if (b < 10240) {
        int idx = b - 4096;
        int c0 = (idx % 96) * 32, r0 = (idx / 96) * 32;
#pragma unroll
        for (int i = 0; i < 4; ++i)
            tile[ty + i * 8][tx] = w_qkv[(long)(r0 + ty + i * 8) * QKV_N + c0 + tx];
        __syncthreads();
#pragma unroll
        for (int i = 0; i < 4; ++i)
            wqt[(long)(c0 + ty + i * 8) * HIDDEN + r0 + tx] = f2bf(tile[tx][ty + i * 8]);
    } else if (b < 14336) {
        int idx = b - 10240;
        int c0 = (idx % 64) * 32, r0 = (idx / 64) * 32;
#pragma unroll
        for (int i = 0; i < 4; ++i)
            tile[ty + i * 8][tx] = w_o[(long)(r0 + ty + i * 8) * HIDDEN + c0 + tx];
        __syncthreads();
#pragma unroll
        for (int i = 0; i < 4; ++i)
            wot[(long)(c0 + ty + i * 8) * HIDDEN + r0 + tx] = f2bf(tile[tx][ty + i * 8]);
    } else {
        int idx = b - 14336;
        int t = idx * 4 + (tid >> 6);
        int j = tid & 63;
        int row = (j >= 44) ? 0 : ((j & 1) ? 2 : 1);
        int pos = positions[row * T + t];
        float invf = exp2f((float)j * -0.29580571f);   // log2(500000)/64
        float ang = (float)pos * invf;
        cosT[t * 64 + j] = cosf(ang);
        sinT[t * 64 + j] = sinf(ang);
    }
}

// ---------------- qkv GEMM: 64x128 tile, BK=64, dbuf async, XOR-swizzled LDS, rope fused -------
// BK=64: 32 iters x 16 MFMA/wave (half the barriers of BK=32). Row stride 64 shorts = 32 words
// means un-swizzled reads would put all 16 m-lanes on one 4-bank group (16-way conflict), so
// chunk c of row r is stored at slot c^(r&7); reads use slot (kk*4+qd)^(m&7) -> 8 lanes per
// 4-bank group = structural minimum for b128.
__global__ __launch_bounds__(256) void gemm_qkv(const unsigned short* __restrict__ A,
                                                const unsigned short* __restrict__ B,
                                                const float* __restrict__ cosT,
                                                const float* __restrict__ sinT,
                                                unsigned short* __restrict__ qb,
                                                unsigned short* __restrict__ kb,
                                                unsigned short* __restrict__ vt) {
    __shared__ __align__(16) unsigned short As[2][64 * 64];    // 2 x 8 KB
    __shared__ __align__(16) unsigned short Bs[2][128 * 64];   // 2 x 16 KB
    const int K = HIDDEN;
    const int tid = threadIdx.x;
    const int wv = tid >> 6;
    const int lane = tid & 63;
    const int m = lane & 15, qd = lane >> 4;
    const unsigned short* Ab = A + (long)(blockIdx.x * 64) * K;
    const unsigned short* Bb = B + (long)(blockIdx.y * 128) * K;

    floatx4 acc[4][2];
#pragma unroll
    for (int i = 0; i < 4; ++i)
#pragma unroll
        for (int j = 0; j < 2; ++j) acc[i][j] = (floatx4){0.f, 0.f, 0.f, 0.f};

#define QKV_STAGE(buf, k0)                                                                   \
    do {                                                                                     \
        _Pragma("unroll") for (int i_ = 0; i_ < 2; ++i_) {                                   \
            int s_ = i_ * 256 + tid, r_ = s_ >> 3, c_ = (s_ & 7) ^ (r_ & 7);                 \
            gload_lds16(Ab + (long)r_ * K + (k0) + c_ * 8, &As[buf][i_ * 2048 + wv * 512]);  \
        }                                                                                    \
        _Pragma("unroll") for (int i_ = 0; i_ < 4; ++i_) {                                   \
            int s_ = i_ * 256 + tid, r_ = s_ >> 3, c_ = (s_ & 7) ^ (r_ & 7);                 \
            gload_lds16(Bb + (long)r_ * K + (k0) + c_ * 8, &Bs[buf][i_ * 2048 + wv * 512]);  \
        }                                                                                    \
    } while (0)

    QKV_STAGE(0, 0);
    int cur = 0;
    for (int k0 = 0; k0 < K; k0 += 64) {
        __syncthreads();                       // buf[cur] landed; prev readers of buf[cur^1] done
        if (k0 + 64 < K) QKV_STAGE(cur ^ 1, k0 + 64);
#pragma unroll
        for (int kk = 0; kk < 2; ++kk) {
            const int rch = ((kk * 4 + qd) ^ (m & 7)) * 8;
            short8 a[4], b[2];
#pragma unroll
            for (int i = 0; i < 4; ++i) a[i] = *(const short8*)&As[cur][(i * 16 + m) * 64 + rch];
#pragma unroll
            for (int j = 0; j < 2; ++j) b[j] = *(const short8*)&Bs[cur][(wv * 32 + j * 16 + m) * 64 + rch];
#pragma unroll
            for (int i = 0; i < 4; ++i)
#pragma unroll
                for (int j = 0; j < 2; ++j)
                    acc[i][j] = __builtin_amdgcn_mfma_f32_16x16x32_bf16(a[i], b[j], acc[i][j], 0, 0, 0);
        }
        cur ^= 1;
    }
#undef QKV_STAGE

    const int by = blockIdx.y;
    if (by < 20) {
        // rope path (q: by<16, k: 16..19); pairs are adjacent cols -> shfl_xor(val,1)
        const float sgn = (m & 1) ? 1.f : -1.f;
        const float qscale = 0.08838834764831845f;   // 1/sqrt(128)
#pragma unroll
        for (int i = 0; i < 4; ++i) {
#pragma unroll
            for (int r = 0; r < 4; ++r) {
                const int t = blockIdx.x * 64 + i * 16 + qd * 4 + r;
                const float* ct = cosT + t * 64;
                const float* st = sinT + t * 64;
#pragma unroll
                for (int j = 0; j < 2; ++j) {
                    const int cq = wv * 32 + j * 16 + m;
                    const int j2 = cq >> 1;
                    float val = acc[i][j][r];
                    float prt = __shfl_xor(val, 1);
                    float o = val * ct[j2] + sgn * prt * st[j2];
                    const int col = by * 128 + cq;
                    if (by < 16) qb[(long)t * Q_SIZE + col] = f2bf(o * qscale);
                    else         kb[(long)t * KV_SIZE + (col - 2048)] = f2bf(o);
                }
            }
        }
    } else {
        // v path: write V^T directly: vt[g][d][t]
        const int g = by - 20;
#pragma unroll
        for (int i = 0; i < 4; ++i)
#pragma unroll
            for (int j = 0; j < 2; ++j) {
                const int d = wv * 32 + j * 16 + m;
                const int t0 = blockIdx.x * 64 + i * 16 + qd * 4;
                unsigned short o4[4];
#pragma unroll
                for (int r = 0; r < 4; ++r) o4[r] = f2bf(acc[i][j][r]);
                *(short4v*)&vt[((long)g * HD + d) * T + t0] = *(short4v*)o4;
            }
    }
}

// ---------------- out GEMM: 64x128 tile, BK=64, dbuf async, XOR-swizzled: C(fp32) = A * B^T ----
__global__ __launch_bounds__(256) void gemm_out(const unsigned short* __restrict__ A,
                                                const unsigned short* __restrict__ B,
                                                float* __restrict__ C,
                                                int K, int ldc) {
    __shared__ __align__(16) unsigned short As[2][64 * 64];
    __shared__ __align__(16) unsigned short Bs[2][128 * 64];
    const int tid = threadIdx.x;
    const int wv = tid >> 6;
    const int lane = tid & 63;
    const int m = lane & 15, qd = lane >> 4;
    const unsigned short* Ab = A + (long)(blockIdx.x * 64) * K;
    const unsigned short* Bb = B + (long)(blockIdx.y * 128) * K;

    floatx4 acc[4][2];
#pragma unroll
    for (int i = 0; i < 4; ++i)
#pragma unroll
        for (int j = 0; j < 2; ++j) acc[i][j] = (floatx4){0.f, 0.f, 0.f, 0.f};

#define OUT_STAGE(buf, k0)                                                                   \
    do {                                                                                     \
        _Pragma("unroll") for (int i_ = 0; i_ < 2; ++i_) {                                   \
            int s_ = i_ * 256 + tid, r_ = s_ >> 3, c_ = (s_ & 7) ^ (r_ & 7);                 \
            gload_lds16(Ab + (long)r_ * K + (k0) + c_ * 8, &As[buf][i_ * 2048 + wv * 512]);  \
        }                                                                                    \
        _Pragma("unroll") for (int i_ = 0; i_ < 4; ++i_) {                                   \
            int s_ = i_ * 256 + tid, r_ = s_ >> 3, c_ = (s_ & 7) ^ (r_ & 7);                 \
            gload_lds16(Bb + (long)r_ * K + (k0) + c_ * 8, &Bs[buf][i_ * 2048 + wv * 512]);  \
        }                                                                                    \
    } while (0)

    OUT_STAGE(0, 0);
    int cur = 0;
    for (int k0 = 0; k0 < K; k0 += 64) {
        __syncthreads();
        if (k0 + 64 < K) OUT_STAGE(cur ^ 1, k0 + 64);
#pragma unroll
        for (int kk = 0; kk < 2; ++kk) {
            const int rch = ((kk * 4 + qd) ^ (m & 7)) * 8;
            short8 a[4], b[2];
#pragma unroll
            for (int i = 0; i < 4; ++i) a[i] = *(const short8*)&As[cur][(i * 16 + m) * 64 + rch];
#pragma unroll
            for (int j = 0; j < 2; ++j) b[j] = *(const short8*)&Bs[cur][(wv * 32 + j * 16 + m) * 64 + rch];
#pragma unroll
            for (int i = 0; i < 4; ++i)
#pragma unroll
                for (int j = 0; j < 2; ++j)
                    acc[i][j] = __builtin_amdgcn_mfma_f32_16x16x32_bf16(a[i], b[j], acc[i][j], 0, 0, 0);
        }
        cur ^= 1;
    }
#undef OUT_STAGE

#pragma unroll
    for (int i = 0; i < 4; ++i)
#pragma unroll
        for (int j = 0; j < 2; ++j)
#pragma unroll
            for (int r = 0; r < 4; ++r)
                C[(long)(blockIdx.x * 64 + i * 16 + qd * 4 + r) * ldc +
                  blockIdx.y * 128 + wv * 32 + j * 16 + m] = acc[i][j][r];
}

// ---------------- flash attention v9: one (qt,half) unit per block, heavy/light CU pairing ----
__global__ __launch_bounds__(256, 2) void flash_attn(const unsigned short* __restrict__ qb,
                                                     const unsigned short* __restrict__ kb,
                                                     const unsigned short* __restrict__ vt,
                                                     float* __restrict__ Opart,
                                                     float* __restrict__ MLpart) {
    __shared__ __align__(16) unsigned short Kbuf[2][64 * 128];   // 32 KB
    __shared__ __align__(16) unsigned short Vbuf[128 * 64];      // 16 KB
    __shared__ __align__(16) unsigned short Pls[4][32 * 72];     // 18.4 KB

    const int tid = threadIdx.x;
    const int wv = tid >> 6;
    const int lane = tid & 63;
    const int m = lane & 15;
    const int qd = lane >> 4;

    const int bx = blockIdx.x;
    const int c_ = bx & 255;
    const int hi = bx >> 8;
    const int h = c_ >> 4;
    const int j_ = c_ & 15;
    const int qt = hi ? (j_ >> 1) : (15 - (j_ >> 1));
    const int half = j_ & 1;
    const int g = h >> 2;
    unsigned short* myP = Pls[wv];

    const int n0 = qt + 1;
    const int jt0 = half ? n0 : 0;
    const int jt1 = half ? 2 * qt + 2 : n0;
    const int q0 = qt * 128;

    short8 aq[2][4];
#pragma unroll
    for (int s = 0; s < 2; ++s)
#pragma unroll
        for (int kk = 0; kk < 4; ++kk)
            aq[s][kk] = *(const short8*)(qb + (long)(q0 + s * 64 + wv * 16 + m) * Q_SIZE +
                                         h * HD + kk * 32 + qd * 8);

    floatx4 acc_o[2][8];
#pragma unroll
    for (int s = 0; s < 2; ++s)
#pragma unroll
        for (int nb = 0; nb < 8; ++nb) acc_o[s][nb] = (floatx4){0.f, 0.f, 0.f, 0.f};
    float mrow[2] = {-1e30f, -1e30f};
    float lrow[2] = {0.f, 0.f};

    // stage first K tile (XOR chunk swizzle c^(r&15))
#pragma unroll
    for (int i = 0; i < 4; ++i) {
        int s_ = i * 256 + tid;
        int r = s_ >> 4, c = (s_ & 15) ^ (r & 15);
        gload_lds16(kb + (long)(jt0 * 64 + r) * KV_SIZE + g * HD + c * 8,
                    &Kbuf[0][i * 2048 + wv * 512]);
    }
    int cur = 0;
    for (int jt = jt0; jt < jt1; ++jt) {
        __syncthreads();   // K[cur] landed; all prior LDS readers done

        if (jt + 1 < jt1) {   // K prefetch -> other buffer (full iter to land)
#pragma unroll
            for (int i = 0; i < 4; ++i) {
                int s_ = i * 256 + tid;
                int r = s_ >> 4, c = (s_ & 15) ^ (r & 15);
                gload_lds16(kb + (long)((jt + 1) * 64 + r) * KV_SIZE + g * HD + c * 8,
                            &Kbuf[cur ^ 1][i * 2048 + wv * 512]);
            }
        }
        // V for CURRENT tile (single buffer; consumed after mid barrier)
#pragma unroll
        for (int i = 0; i < 4; ++i) {
            int s_ = i * 256 + tid;
            int r = s_ >> 3, c = (s_ & 7) ^ (r & 7);
            gload_lds16(vt + ((long)g * HD + r) * T + jt * 64 + c * 8,
                        &Vbuf[i * 2048 + wv * 512]);
        }

        // S^T = K Q^T for both q-sets, sharing K fragment loads
        floatx4 acc_s[2][4];
#pragma unroll
        for (int s = 0; s < 2; ++s)
#pragma unroll
            for (int c = 0; c < 4; ++c) acc_s[s][c] = (floatx4){0.f, 0.f, 0.f, 0.f};
#pragma unroll
        for (int kk = 0; kk < 4; ++kk) {
#pragma unroll
            for (int c = 0; c < 4; ++c) {
                short8 ak = *(const short8*)&Kbuf[cur][(c * 16 + m) * 128 +
                                                       (((4 * kk + qd) ^ m) * 8)];
                acc_s[0][c] = __builtin_amdgcn_mfma_f32_16x16x32_bf16(ak, aq[0][kk], acc_s[0][c], 0, 0, 0);
                acc_s[1][c] = __builtin_amdgcn_mfma_f32_16x16x32_bf16(ak, aq[1][kk], acc_s[1][c], 0, 0, 0);
            }
        }

        // per-set online softmax + P write
#pragma unroll
        for (int s = 0; s < 2; ++s) {
            const int dg = 2 * qt + s;
            if (jt >= dg) {
                const bool full = (jt > dg);
#pragma unroll
                for (int c = 0; c < 4; ++c)
#pragma unroll
                    for (int r = 0; r < 4; ++r)
                        if (full || (c * 16 + qd * 4 + r > wv * 16 + m)) acc_s[s][c][r] = -1e30f;
            }
            float mx = acc_s[s][0][0];
#pragma unroll
            for (int c = 0; c < 4; ++c)
#pragma unroll
                for (int r = 0; r < 4; ++r) mx = fmaxf(mx, acc_s[s][c][r]);
            mx = fmaxf(mx, __shfl_xor(mx, 16));
            mx = fmaxf(mx, __shfl_xor(mx, 32));
            float mnew = fmaxf(mrow[s], mx);
            float alpha = __expf(mrow[s] - mnew);
            mrow[s] = mnew;

            float pv[4][4];
            float lsum = 0.f;
#pragma unroll
            for (int c = 0; c < 4; ++c)
#pragma unroll
                for (int r = 0; r < 4; ++r) {
                    pv[c][r] = __expf(acc_s[s][c][r] - mnew);
                    lsum += pv[c][r];
                }
            lsum += __shfl_xor(lsum, 16);
            lsum += __shfl_xor(lsum, 32);
            lrow[s] = lrow[s] * alpha + lsum;
#pragma unroll
            for (int nb = 0; nb < 8; ++nb)
#pragma unroll
                for (int r = 0; r < 4; ++r) acc_o[s][nb][r] *= alpha;
#pragma unroll
            for (int c = 0; c < 4; ++c) {
                short4v pk = {(short)f2bf(pv[c][0]), (short)f2bf(pv[c][1]),
                              (short)f2bf(pv[c][2]), (short)f2bf(pv[c][3])};
                *(short4v*)&myP[(s * 16 + m) * 72 + c * 16 + qd * 4] = pk;
            }
        }

        __syncthreads();   // V landed (and block-wide sync)

        // PV for both sets, sharing V fragment loads
#pragma unroll
        for (int kk = 0; kk < 2; ++kk) {
            short8 pa0 = *(const short8*)&myP[m * 72 + kk * 32 + qd * 8];
            short8 pa1 = *(const short8*)&myP[(16 + m) * 72 + kk * 32 + qd * 8];
#pragma unroll
            for (int nb = 0; nb < 8; ++nb) {
                short8 av = *(const short8*)&Vbuf[(nb * 16 + m) * 64 +
                                                  (((4 * kk + qd) ^ (m & 7)) * 8)];
                acc_o[0][nb] = __builtin_amdgcn_mfma_f32_16x16x32_bf16(av, pa0, acc_o[0][nb], 0, 0, 0);
                acc_o[1][nb] = __builtin_amdgcn_mfma_f32_16x16x32_bf16(av, pa1, acc_o[1][nb], 0, 0, 0);
            }
        }
        cur ^= 1;
    }

    // store partials for this unit
    const int unit = (h * 16 + qt) * 2 + half;
#pragma unroll
    for (int s = 0; s < 2; ++s) {
        const long rb = (long)unit * 128 + s * 64 + wv * 16 + m;
#pragma unroll
        for (int nb = 0; nb < 8; ++nb)
            *(floatx4*)&Opart[rb * 128 + nb * 16 + qd * 4] = acc_o[s][nb];
        if (qd == 0) {
            MLpart[rb * 2]     = mrow[s];
            MLpart[rb * 2 + 1] = lrow[s];
        }
    }
}

// ---------------- combine K-split partials -> ab bf16 [t][h*128+d] ----------------
__global__ __launch_bounds__(256) void attn_combine(const float* __restrict__ Opart,
                                                    const float* __restrict__ MLpart,
                                                    unsigned short* __restrict__ ab) {
    const int tid = threadIdx.x;
    const int q = blockIdx.x * 16 + (tid >> 4);
    const int h = blockIdx.y;
    const int d0 = (tid & 15) * 8;
    const int qt = q >> 7, lr = q & 127;
    const long r0 = ((long)(h * 16 + qt) * 2) * 128 + lr;
    const long r1 = r0 + 128;
    float m0 = MLpart[r0 * 2], l0 = MLpart[r0 * 2 + 1];
    float m1 = MLpart[r1 * 2], l1 = MLpart[r1 * 2 + 1];
    float M = fmaxf(m0, m1);
    float a0 = __expf(m0 - M), a1 = __expf(m1 - M);
    float inv = 1.f / (l0 * a0 + l1 * a1);
    const float* O0 = Opart + r0 * 128 + d0;
    const float* O1 = Opart + r1 * 128 + d0;
    unsigned short outv[8];
#pragma unroll
    for (int j = 0; j < 8; j += 4) {
        float4 x0 = *(const float4*)(O0 + j);
        float4 x1 = *(const float4*)(O1 + j);
        outv[j]     = f2bf((x0.x * a0 + x1.x * a1) * inv);
        outv[j + 1] = f2bf((x0.y * a0 + x1.y * a1) * inv);
        outv[j + 2] = f2bf((x0.z * a0 + x1.z * a1) * inv);
        outv[j + 3] = f2bf((x0.w * a0 + x1.w * a1) * inv);
    }
    *(short8*)&ab[(long)q * Q_SIZE + h * HD + d0] = *(short8*)outv;
}

extern "C" void kernel_launch(void* const* d_in, const int* in_sizes, int n_in,
                              void* d_out, int out_size, void* d_ws, size_t ws_size,
                              hipStream_t stream) {
    const int* positions = (const int*)d_in[0];
    const float* hidden  = (const float*)d_in[1];
    const float* w_qkv   = (const float*)d_in[2];
    const float* w_o     = (const float*)d_in[3];
    float* out = (float*)d_out;

    char* p = (char*)d_ws;
    auto alloc = [&](size_t bytes) { char* r = p; p += (bytes + 255) & ~(size_t)255; return r; };
    float* cosT = (float*)alloc((size_t)T * 64 * 4);
    float* sinT = (float*)alloc((size_t)T * 64 * 4);
    unsigned short* hb  = (unsigned short*)alloc((size_t)T * HIDDEN * 2);
    unsigned short* wqt = (unsigned short*)alloc((size_t)QKV_N * HIDDEN * 2);
    unsigned short* wot = (unsigned short*)alloc((size_t)HIDDEN * HIDDEN * 2);
    unsigned short* qb  = (unsigned short*)alloc((size_t)T * Q_SIZE * 2);
    unsigned short* kb  = (unsigned short*)alloc((size_t)T * KV_SIZE * 2);
    unsigned short* vt  = (unsigned short*)alloc((size_t)T * KV_SIZE * 2);
    unsigned short* ab  = (unsigned short*)alloc((size_t)T * Q_SIZE * 2);
    float* Opart  = (float*)alloc((size_t)512 * 128 * 128 * 4);   // 33.5 MB
    float* MLpart = (float*)alloc((size_t)512 * 128 * 2 * 4);

    // 1) fused prep (convert + 2 transposes + cos/sin tables)
    prep_misc<<<dim3(14848), 256, 0, stream>>>(hidden, w_qkv, w_o, positions,
                                               hb, wqt, wot, cosT, sinT);
    // 2) fused qkv projection + rope -> qb (scaled), kb, vt (BK=64)
    gemm_qkv<<<dim3(T / 64, QKV_N / 128), 256, 0, stream>>>(hb, wqt, cosT, sinT, qb, kb, vt);
    // 3) fused causal attention, 512 single-unit blocks, heavy+light per CU
    flash_attn<<<dim3(512), 256, 0, stream>>>(qb, kb, vt, Opart, MLpart);
    // 4) combine partials
    attn_combine<<<dim3(T / 16, NH), 256, 0, stream>>>(Opart, MLpart, ab);
    // 5) out = attn @ w_o (BK=64)
    gemm_out<<<dim3(T / 64, HIDDEN / 128), 256, 0, stream>>>(ab, wot, out, Q_SIZE, HIDDEN);
}